// Round 1
// baseline (410.559 us; speedup 1.0000x reference)
//
#include <hip/hip_runtime.h>
#include <cstdint>

static constexpr int S = 1024;
static constexpr int T = 32;
static constexpr float L2E  = 1.4426950408889634f;  // log2(e)
static constexpr float LN2f = 0.6931471805599453f;  // ln(2)

__global__ void crf_zero(float* ws) {
  ws[0] = 0.0f;
  ws[1] = 0.0f;
}

__global__ void crf_fin(const float* __restrict__ ws, float* __restrict__ out) {
  out[0] = ws[0] / (ws[1] + 1e-6f);
}

__device__ __forceinline__ float bcast_lane(float v, int k) {
  return __uint_as_float((unsigned)__builtin_amdgcn_readlane((int)__float_as_uint(v), k));
}

// One wave (64 threads) per batch. Lane t (= lane&31) owns forward value e_t,
// duplicated across the two half-waves. Linear-domain forward scan:
//   e'_t = (sum_i e_i * P[i][t]) * 2^(em'_jt), running log2-scale M.
__global__ __launch_bounds__(64, 1) void crf_main(
    const float* __restrict__ em, const int* __restrict__ tags,
    const int* __restrict__ mask, const float* __restrict__ startT,
    const float* __restrict__ trans, const float* __restrict__ endT,
    float* __restrict__ ws)
{
  __shared__ float s_em[2][64 * T];   // 2 x 8 KiB emission staging
  __shared__ int   s_mask[S];         // 4 KiB
  __shared__ int   s_tags[S];         // 4 KiB
  __shared__ float s_trans[T * T];    // 4 KiB (raw, for numerator gathers)

  const int b    = blockIdx.x;
  const int lane = threadIdx.x;
  const int t    = lane & 31;

  const float* emb   = em   + (size_t)b * S * T;
  const int*   maskb = mask + (size_t)b * S;
  const int*   tagsb = tags + (size_t)b * S;

  // ---- pre-pass: stage mask/tags, find head/tail/count (wave-uniform) ----
  int head = S - 1, tail = 0, cnt = 0;
  for (int i = lane; i < S; i += 64) {
    int mw = maskb[i];
    int tg = tagsb[i];
    s_mask[i] = mw;
    s_tags[i] = tg;
    unsigned long long bal = __ballot(mw != 0);
    if (bal) {
      int base = i - lane;
      head = min(head, base + (int)__builtin_ctzll(bal));
      tail = max(tail, base + 63 - (int)__builtin_clzll(bal));
      cnt += (int)__builtin_popcountll(bal);
    }
  }
  for (int i = lane; i < T * T; i += 64) s_trans[i] = trans[i];

  // ---- P column for this lane's target t: P[i][t] = 2^(trans[i][t]*L2E) ----
  float P[T];
  #pragma unroll
  for (int i = 0; i < T; ++i) P[i] = exp2f(trans[i * T + t] * L2E);

  // ---- init: score0 = start + em[head], to linear domain with scale M ----
  float sc0 = (startT[t] + emb[head * T + t]) * L2E;
  float m0 = sc0;
  #pragma unroll
  for (int d = 1; d < 32; d <<= 1) m0 = fmaxf(m0, __shfl_xor(m0, d));
  float e = exp2f(sc0 - m0);
  float M = m0;

  const int nblk = tail / 64 + 1;   // early exit past last valid step

  // prefetch block 0 into registers
  float4 pf[8];
  {
    const float4* src = (const float4*)emb;
    #pragma unroll
    for (int n = 0; n < 8; ++n) pf[n] = src[n * 64 + lane];
  }

  float numer = 0.0f;
  int applied = 0;
  int buf = 0;

  for (int blk = 0; blk < nblk; ++blk) {
    // commit staged registers to LDS
    {
      float4* dst = (float4*)(&s_em[buf][0]);
      #pragma unroll
      for (int n = 0; n < 8; ++n) dst[n * 64 + lane] = pf[n];
    }
    __syncthreads();
    // issue next block's global loads (in flight during the 64-step scan)
    if (blk + 1 < nblk) {
      const float4* src = (const float4*)(emb + (size_t)(blk + 1) * 64 * T);
      #pragma unroll
      for (int n = 0; n < 8; ++n) pf[n] = src[n * 64 + lane];
    }

    // 64-bit mask for this block's steps (wave-uniform SGPR pair)
    unsigned long long mb = __ballot(s_mask[blk * 64 + lane] != 0);
    const float* emblk = &s_em[buf][0];

    for (int jj = 0; jj < 64; ++jj) {
      int j = blk * 64 + jj;
      if (j < 1 || j == head) continue;          // uniform skip
      if (!((mb >> jj) & 1ull)) continue;        // uniform skip (cond false)

      // D_t = sum_i e_i * P[i][t]; e_i broadcast from lane i via v_readlane
      float d0 = 0.f, d1 = 0.f, d2 = 0.f, d3 = 0.f;
      #pragma unroll
      for (int k = 0; k < 32; k += 4) {
        d0 = fmaf(bcast_lane(e, k + 0), P[k + 0], d0);
        d1 = fmaf(bcast_lane(e, k + 1), P[k + 1], d1);
        d2 = fmaf(bcast_lane(e, k + 2), P[k + 2], d2);
        d3 = fmaf(bcast_lane(e, k + 3), P[k + 3], d3);
      }
      float D = (d0 + d1) + (d2 + d3);
      float g = exp2f(emblk[jj * T + t] * L2E);
      float enew = D * g;

      ++applied;
      if ((applied & 3) == 0) {                  // exponent rescale, every 4
        unsigned r = (unsigned)__builtin_amdgcn_readlane((int)__float_as_uint(enew), 0);
        int K = (int)((r >> 23) & 0xffu) - 127;
        enew *= __uint_as_float((unsigned)(127 - K) << 23);   // * 2^-K
        M += (float)K;
      }
      e = enew;
    }

    // ---- numerator contribution for this block (lane <-> step jj) ----
    {
      int j = blk * 64 + lane;
      if (j >= 1 && j != head && s_mask[j] != 0) {
        int tg = s_tags[j];
        int tp = s_tags[j - 1];
        numer += s_trans[tp * T + tg] + emblk[lane * T + tg];
      }
    }
    __syncthreads();
    buf ^= 1;
  }

  // ---- denominator: M + log2(sum_t e_t * 2^(end'_t)), back to natural log ----
  float fv = e * exp2f(endT[t] * L2E);
  #pragma unroll
  for (int d = 1; d < 32; d <<= 1) fv += __shfl_xor(fv, d);
  float denom = (M + log2f(fv)) * LN2f;

  #pragma unroll
  for (int d = 1; d < 64; d <<= 1) numer += __shfl_xor(numer, d);

  if (lane == 0 && cnt > 0) {
    int th_ = s_tags[head];
    int tt_ = s_tags[tail];
    float numtot = numer + startT[th_] + emb[head * T + th_] + endT[tt_];
    float llh = denom - numtot;
    atomicAdd(&ws[0], llh / ((float)cnt + 1e-6f));
    atomicAdd(&ws[1], 1.0f);
  }
}

extern "C" void kernel_launch(void* const* d_in, const int* in_sizes, int n_in,
                              void* d_out, int out_size, void* d_ws, size_t ws_size,
                              hipStream_t stream) {
  const float* em     = (const float*)d_in[0];
  const int*   tags   = (const int*)d_in[1];
  const int*   mask   = (const int*)d_in[2];
  const float* startT = (const float*)d_in[3];
  const float* trans  = (const float*)d_in[4];
  const float* endT   = (const float*)d_in[5];
  float* out = (float*)d_out;
  float* ws  = (float*)d_ws;

  const int B = in_sizes[0] / (S * T);

  crf_zero<<<1, 1, 0, stream>>>(ws);
  crf_main<<<B, 64, 0, stream>>>(em, tags, mask, startT, trans, endT, ws);
  crf_fin<<<1, 1, 0, stream>>>(ws, out);
}

// Round 2
// 315.410 us; speedup vs baseline: 1.3017x; 1.3017x over previous
//
#include <hip/hip_runtime.h>
#include <cstdint>

static constexpr int S = 1024;
static constexpr int T = 32;
static constexpr float L2E  = 1.4426950408889634f;  // log2(e)
static constexpr float LN2f = 0.6931471805599453f;  // ln(2)

__global__ void crf_zero(float* ws) {
  ws[0] = 0.0f;
  ws[1] = 0.0f;
}

__global__ void crf_fin(const float* __restrict__ ws, float* __restrict__ out) {
  out[0] = ws[0] / (ws[1] + 1e-6f);
}

__device__ __forceinline__ float bcast_lane(float v, int k) {
  return __uint_as_float((unsigned)__builtin_amdgcn_readlane((int)__float_as_uint(v), k));
}

// One wave (64 threads) per batch. Lane t (= lane&31) owns forward value e_t,
// duplicated across the two half-waves. Linear-domain forward scan:
//   e'_t = (sum_i e_i * P[i][t]) * g_jt,  g_jt = 2^(em_jt*log2e), scale M.
// g is precomputed into LDS at block staging so the per-step chain is only
// readlane-broadcast + fma + mul + select.
__global__ __launch_bounds__(64, 1) void crf_main(
    const float* __restrict__ em, const int* __restrict__ tags,
    const int* __restrict__ mask, const float* __restrict__ startT,
    const float* __restrict__ trans, const float* __restrict__ endT,
    float* __restrict__ ws)
{
  __shared__ float s_g[2][64 * T];    // 2 x 8 KiB staged g = 2^(em')
  __shared__ int   s_mask[S];         // 4 KiB
  __shared__ int   s_tags[S];         // 4 KiB
  __shared__ float s_trans[T * T];    // 4 KiB (raw, for numerator gathers)

  const int b    = blockIdx.x;
  const int lane = threadIdx.x;
  const int t    = lane & 31;

  const float* emb   = em   + (size_t)b * S * T;
  const int*   maskb = mask + (size_t)b * S;
  const int*   tagsb = tags + (size_t)b * S;

  // ---- pre-pass: stage mask/tags, find head/tail/count (wave-uniform) ----
  int head = S - 1, tail = 0, cnt = 0;
  for (int i = lane; i < S; i += 64) {
    int mw = maskb[i];
    int tg = tagsb[i];
    s_mask[i] = mw;
    s_tags[i] = tg;
    unsigned long long bal = __ballot(mw != 0);
    if (bal) {
      int base = i - lane;   // uniform
      head = min(head, base + (int)__builtin_ctzll(bal));
      tail = max(tail, base + 63 - (int)__builtin_clzll(bal));
      cnt += (int)__builtin_popcountll(bal);
    }
  }
  for (int i = lane; i < T * T; i += 64) s_trans[i] = trans[i];

  // ---- P column for this lane's target t: P[i][t] = 2^(trans[i][t]*L2E) ----
  float P[T];
  #pragma unroll
  for (int i = 0; i < T; ++i) P[i] = exp2f(trans[i * T + t] * L2E);

  // ---- init: score0 = start + em[head], to linear domain with scale M ----
  float sc0 = (startT[t] + emb[head * T + t]) * L2E;
  float m0 = sc0;
  #pragma unroll
  for (int d = 1; d < 32; d <<= 1) m0 = fmaxf(m0, __shfl_xor(m0, d));
  float e = exp2f(sc0 - m0);
  float M = m0;

  const int nblk = tail / 64 + 1;   // early exit past last valid step

  // prefetch block 0 into registers
  float4 pf[8];
  {
    const float4* src = (const float4*)emb;
    #pragma unroll
    for (int n = 0; n < 8; ++n) pf[n] = src[n * 64 + lane];
  }

  float numer = 0.0f;
  int buf = 0;

  for (int blk = 0; blk < nblk; ++blk) {
    // commit staged registers to LDS, transforming em -> g = 2^(em*L2E).
    // (single wave per block: no __syncthreads needed, program order + waitcnt)
    {
      float4* dst = (float4*)(&s_g[buf][0]);
      #pragma unroll
      for (int n = 0; n < 8; ++n) {
        float4 v = pf[n];
        v.x = exp2f(v.x * L2E);
        v.y = exp2f(v.y * L2E);
        v.z = exp2f(v.z * L2E);
        v.w = exp2f(v.w * L2E);
        dst[n * 64 + lane] = v;
      }
    }
    // issue next block's global loads (in flight during the 64-step scan)
    if (blk + 1 < nblk) {
      const float4* src = (const float4*)(emb + (size_t)(blk + 1) * 64 * T);
      #pragma unroll
      for (int n = 0; n < 8; ++n) pf[n] = src[n * 64 + lane];
    }

    // 64-bit applied-mask for this block's steps (wave-uniform)
    unsigned long long mb = __ballot(s_mask[blk * 64 + lane] != 0);
    const float* gbuf = &s_g[buf][0];

    for (int jj2 = 0; jj2 < 64; jj2 += 16) {
      // batch-load this chunk's g values (pipelined ds_read_b32)
      float gg[16];
      #pragma unroll
      for (int k = 0; k < 16; ++k) gg[k] = gbuf[(jj2 + k) * T + t];

      #pragma unroll
      for (int k = 0; k < 16; ++k) {
        const int kk = jj2 + k;
        const int j  = blk * 64 + kk;
        const bool apply = (j >= 1) && (j != head) && (((mb >> kk) & 1ull) != 0ull);

        float d0 = 0.f, d1 = 0.f, d2 = 0.f, d3 = 0.f;
        #pragma unroll
        for (int q = 0; q < 32; q += 4) {
          d0 = fmaf(bcast_lane(e, q + 0), P[q + 0], d0);
          d1 = fmaf(bcast_lane(e, q + 1), P[q + 1], d1);
          d2 = fmaf(bcast_lane(e, q + 2), P[q + 2], d2);
          d3 = fmaf(bcast_lane(e, q + 3), P[q + 3], d3);
        }
        float enew = ((d0 + d1) + (d2 + d3)) * gg[k];
        e = apply ? enew : e;

        if ((kk & 7) == 7) {   // exponent rescale, every 8 steps (always valid)
          unsigned r = (unsigned)__builtin_amdgcn_readlane((int)__float_as_uint(e), 0);
          int K = (int)((r >> 23) & 0xffu) - 127;
          e *= __uint_as_float((unsigned)(127 - K) << 23);   // * 2^-K
          M += (float)K;
        }
      }
    }

    // ---- numerator contribution for this block (lane <-> step in block) ----
    {
      int j = blk * 64 + lane;
      if (j >= 1 && j != head && s_mask[j] != 0) {
        int tg = s_tags[j];
        int tp = s_tags[j - 1];
        // em recovered from staged g: em = log2(g)*ln2
        numer += s_trans[tp * T + tg] + log2f(gbuf[lane * T + tg]) * LN2f;
      }
    }
    buf ^= 1;
  }

  // ---- denominator: M + log2(sum_t e_t * 2^(end'_t)), back to natural log ----
  float fv = e * exp2f(endT[t] * L2E);
  #pragma unroll
  for (int d = 1; d < 32; d <<= 1) fv += __shfl_xor(fv, d);
  float denom = (M + log2f(fv)) * LN2f;

  #pragma unroll
  for (int d = 1; d < 64; d <<= 1) numer += __shfl_xor(numer, d);

  if (lane == 0 && cnt > 0) {
    int th_ = s_tags[head];
    int tt_ = s_tags[tail];
    float numtot = numer + startT[th_] + emb[head * T + th_] + endT[tt_];
    float llh = denom - numtot;
    atomicAdd(&ws[0], llh / ((float)cnt + 1e-6f));
    atomicAdd(&ws[1], 1.0f);
  }
}

extern "C" void kernel_launch(void* const* d_in, const int* in_sizes, int n_in,
                              void* d_out, int out_size, void* d_ws, size_t ws_size,
                              hipStream_t stream) {
  const float* em     = (const float*)d_in[0];
  const int*   tags   = (const int*)d_in[1];
  const int*   mask   = (const int*)d_in[2];
  const float* startT = (const float*)d_in[3];
  const float* trans  = (const float*)d_in[4];
  const float* endT   = (const float*)d_in[5];
  float* out = (float*)d_out;
  float* ws  = (float*)d_ws;

  const int B = in_sizes[0] / (S * T);

  crf_zero<<<1, 1, 0, stream>>>(ws);
  crf_main<<<B, 64, 0, stream>>>(em, tags, mask, startT, trans, endT, ws);
  crf_fin<<<1, 1, 0, stream>>>(ws, out);
}

// Round 3
// 301.777 us; speedup vs baseline: 1.3605x; 1.0452x over previous
//
#include <hip/hip_runtime.h>
#include <cstdint>

static constexpr int S = 1024;
static constexpr int T = 32;
static constexpr float L2E  = 1.4426950408889634f;  // log2(e)
static constexpr float LN2f = 0.6931471805599453f;  // ln(2)

typedef __attribute__((ext_vector_type(8)))  short  short8;
typedef __attribute__((ext_vector_type(16))) float  float16;

union Frag { unsigned u[4]; short8 s; };

__global__ void crf_zero(float* ws) { ws[0] = 0.0f; ws[1] = 0.0f; }

__global__ void crf_fin(const float* __restrict__ ws, float* __restrict__ out) {
  out[0] = ws[0] / (ws[1] + 1e-6f);
}

__device__ __forceinline__ float bcast_lane(float v, int k) {
  return __uint_as_float((unsigned)__builtin_amdgcn_readlane((int)__float_as_uint(v), k));
}

// pack two f32 -> bf16x2 (hi in high half), round-half-up
__device__ __forceinline__ unsigned packbf(float hi, float lo) {
  unsigned h = __float_as_uint(hi), l = __float_as_uint(lo);
  return ((h + 0x8000u) & 0xFFFF0000u) | ((l + 0x8000u) >> 16);
}

// v_permlane32_swap: x' = [x_lo | y_lo(shifted)], y' = [x_hi(shifted) | y_hi]
__device__ __forceinline__ void plswap(unsigned& x, unsigned& y, bool hih) {
#if __has_builtin(__builtin_amdgcn_permlane32_swap)
  auto r = __builtin_amdgcn_permlane32_swap((int)x, (int)y, false, false);
  x = (unsigned)r[0]; y = (unsigned)r[1];
#else
  unsigned ex = (unsigned)__shfl_xor((int)x, 32, 64);
  unsigned ey = (unsigned)__shfl_xor((int)y, 32, 64);
  unsigned nx = hih ? ey : x;
  unsigned ny = hih ? y  : ex;
  x = nx; y = ny;
#endif
}

// Block = one batch. 8 waves; wave w folds steps [128w, 128w+128) into a
// 32x32 chunk matrix via MFMA (linear 2^x domain: A_j = diag(g_j) P^T,
// M carried in B-operand layout, A = P^T constant). Phase 2: wave 0 scans
// the 8 chunk matrices over the init vector. Numerator fused.
__global__ __launch_bounds__(512, 4) void crf_main(
    const float* __restrict__ em, const int* __restrict__ tags,
    const int* __restrict__ mask, const float* __restrict__ startT,
    const float* __restrict__ trans, const float* __restrict__ endT,
    float* __restrict__ ws)
{
  __shared__ __align__(16) float s_g[8][512];     // per-wave g staging (16 steps x 32)
  __shared__ __align__(16) float s_mats[8][1024]; // chunk matrices, row-major [k][n]
  __shared__ float s_trans[1024];
  __shared__ int   s_tags[1024];
  __shared__ unsigned long long s_mb[16];
  __shared__ int   s_head, s_tail, s_cnt, s_K[8];
  __shared__ float s_num[8];

  const int tid = threadIdx.x;
  const int l   = tid & 63;
  const int wv  = tid >> 6;
  const int b   = blockIdx.x;
  const int n   = l & 31;        // MFMA column / tag index
  const int h   = l >> 5;        // lane half
  const bool hih = (h == 1);

  const float* emb   = em   + (size_t)b * S * T;
  const int*   maskb = mask + (size_t)b * S;
  const int*   tagsb = tags + (size_t)b * S;

  // ---- cooperative staging: tags, trans, mask ballots ----
  for (int i = tid; i < 1024; i += 512) { s_tags[i] = tagsb[i]; s_trans[i] = trans[i]; }
  {
    unsigned long long b0 = __ballot(maskb[wv * 128 + l] != 0);
    unsigned long long b1 = __ballot(maskb[wv * 128 + 64 + l] != 0);
    if (l == 0) { s_mb[2 * wv] = b0; s_mb[2 * wv + 1] = b1; }
  }

  // ---- A = P^T as bf16 frags (constant; lane: m=n, k=8h+j) ----
  Frag Alo, Ahi;
  #pragma unroll
  for (int p = 0; p < 4; ++p) {
    int k0 = 8 * h + 2 * p;
    Alo.u[p] = packbf(exp2f(trans[(k0 + 1)  * T + n] * L2E),
                      exp2f(trans[(k0 + 0)  * T + n] * L2E));
    Ahi.u[p] = packbf(exp2f(trans[(k0 + 17) * T + n] * L2E),
                      exp2f(trans[(k0 + 16) * T + n] * L2E));
  }
  __syncthreads();

  if (wv == 0) {
    int first = 0x7fffffff, last = -1, pc = 0;
    if (l < 16) {
      unsigned long long w = s_mb[l];
      if (w) {
        first = 64 * l + (int)__builtin_ctzll(w);
        last  = 64 * l + 63 - (int)__builtin_clzll(w);
        pc    = (int)__builtin_popcountll(w);
      }
    }
    #pragma unroll
    for (int d = 1; d < 64; d <<= 1) {
      first = min(first, __shfl_xor(first, d));
      last  = max(last,  __shfl_xor(last,  d));
      pc   += __shfl_xor(pc, d);
    }
    if (l == 0) { s_head = first; s_tail = last; s_cnt = pc; }
  }
  __syncthreads();
  const int cnt  = s_cnt;
  const int head = (cnt > 0) ? s_head : 0;
  const int tail = (cnt > 0) ? s_tail : 0;

  // ---- fold phase (per wave, no barriers) ----
  float* sgw = s_g[wv];
  Frag Blo, Bhi;                      // M in B-layout, init = identity
  #pragma unroll
  for (int p = 0; p < 4; ++p) {
    int k0 = 8 * h + 2 * p;
    Blo.u[p] = ((k0 == n)      ? 0x3F80u : 0u) | ((k0 + 1  == n) ? 0x3F800000u : 0u);
    Bhi.u[p] = ((k0 + 16 == n) ? 0x3F80u : 0u) | ((k0 + 17 == n) ? 0x3F800000u : 0u);
  }
  int   Kacc  = 0;
  float numer = 0.0f;
  const int cs = wv * 128;

#define FOLD(JJ, RSC) do {                                                   \
    const float* gr = sgw + (JJ) * T + 4 * h;                                \
    float4 ga = *(const float4*)(gr);                                        \
    float4 gb = *(const float4*)(gr + 8);                                    \
    float4 gc = *(const float4*)(gr + 16);                                   \
    float4 gd = *(const float4*)(gr + 24);                                   \
    float16 D = {0,0,0,0,0,0,0,0,0,0,0,0,0,0,0,0};                           \
    D = __builtin_amdgcn_mfma_f32_32x32x16_bf16(Alo.s, Blo.s, D, 0, 0, 0);   \
    D = __builtin_amdgcn_mfma_f32_32x32x16_bf16(Ahi.s, Bhi.s, D, 0, 0, 0);   \
    D[0]  *= ga.x; D[1]  *= ga.y; D[2]  *= ga.z; D[3]  *= ga.w;              \
    D[4]  *= gb.x; D[5]  *= gb.y; D[6]  *= gb.z; D[7]  *= gb.w;              \
    D[8]  *= gc.x; D[9]  *= gc.y; D[10] *= gc.z; D[11] *= gc.w;              \
    D[12] *= gd.x; D[13] *= gd.y; D[14] *= gd.z; D[15] *= gd.w;              \
    if (RSC) {                                                               \
      float mx = fmaxf(fmaxf(fmaxf(D[0], D[1]), fmaxf(D[2], D[3])),          \
                       fmaxf(fmaxf(D[4], D[5]), fmaxf(D[6], D[7])));         \
      mx = fmaxf(mx, fmaxf(fmaxf(fmaxf(D[8], D[9]),  fmaxf(D[10], D[11])),   \
                           fmaxf(fmaxf(D[12], D[13]), fmaxf(D[14], D[15]))));\
      mx = fmaxf(mx, __shfl_xor(mx, 1));  mx = fmaxf(mx, __shfl_xor(mx, 2)); \
      mx = fmaxf(mx, __shfl_xor(mx, 4));  mx = fmaxf(mx, __shfl_xor(mx, 8)); \
      mx = fmaxf(mx, __shfl_xor(mx, 16)); mx = fmaxf(mx, __shfl_xor(mx, 32));\
      int E = (int)((__float_as_uint(mx) >> 23) & 0xffu);                    \
      float sc = __uint_as_float((unsigned)(254 - E) << 23);                 \
      Kacc += E - 127;                                                       \
      _Pragma("unroll")                                                      \
      for (int q_ = 0; q_ < 16; ++q_) D[q_] *= sc;                           \
    }                                                                        \
    unsigned u0 = packbf(D[1],  D[0]),  u1 = packbf(D[3],  D[2]);            \
    unsigned u2 = packbf(D[5],  D[4]),  u3 = packbf(D[7],  D[6]);            \
    unsigned u4 = packbf(D[9],  D[8]),  u5 = packbf(D[11], D[10]);           \
    unsigned u6 = packbf(D[13], D[12]), u7 = packbf(D[15], D[14]);           \
    plswap(u0, u2, hih); plswap(u1, u3, hih);                                \
    plswap(u4, u6, hih); plswap(u5, u7, hih);                                \
    Blo.u[0] = u0; Blo.u[1] = u1; Blo.u[2] = u2; Blo.u[3] = u3;              \
    Bhi.u[0] = u4; Bhi.u[1] = u5; Bhi.u[2] = u6; Bhi.u[3] = u7;              \
  } while (0)

  for (int sb = 0; sb < 8; ++sb) {
    const int j0 = cs + 16 * sb;
    if (j0 > tail) break;
    unsigned eff = (unsigned)((s_mb[j0 >> 6] >> (j0 & 63)) & 0xFFFFull);
    if (j0 == 0) eff &= ~1u;
    if (head >= j0 && head < j0 + 16) eff &= ~(1u << (head - j0));
    if (eff == 0) continue;

    // stage em -> g = 2^(em*log2e) into this wave's LDS region
    {
      const float4* src = (const float4*)(emb + (size_t)j0 * T);
      float4 v0 = src[l], v1 = src[l + 64];
      v0.x = exp2f(v0.x * L2E); v0.y = exp2f(v0.y * L2E);
      v0.z = exp2f(v0.z * L2E); v0.w = exp2f(v0.w * L2E);
      v1.x = exp2f(v1.x * L2E); v1.y = exp2f(v1.y * L2E);
      v1.z = exp2f(v1.z * L2E); v1.w = exp2f(v1.w * L2E);
      ((float4*)sgw)[l] = v0; ((float4*)sgw)[l + 64] = v1;
    }

    // numerator (lanes 0..15 take one step each)
    if (l < 16 && ((eff >> l) & 1u)) {
      int j  = j0 + l;
      int tg = s_tags[j], tp = s_tags[j - 1];
      numer += s_trans[tp * T + tg] + log2f(sgw[l * T + tg]) * LN2f;
    }

    if (eff == 0xFFFFu) {
      #pragma unroll
      for (int jj = 0; jj < 16; ++jj) FOLD(jj, ((jj & 7) == 7));
    } else {
      for (int jj = 0; jj < 16; ++jj)
        if ((eff >> jj) & 1u) FOLD(jj, true);
    }
  }
#undef FOLD

  // ---- publish chunk matrix (bf16->f32) + numerator partial ----
  #pragma unroll
  for (int p = 0; p < 4; ++p) {
    int k0 = 8 * h + 2 * p;
    s_mats[wv][(k0 + 0)  * T + n] = __uint_as_float(Blo.u[p] << 16);
    s_mats[wv][(k0 + 1)  * T + n] = __uint_as_float(Blo.u[p] & 0xFFFF0000u);
    s_mats[wv][(k0 + 16) * T + n] = __uint_as_float(Bhi.u[p] << 16);
    s_mats[wv][(k0 + 17) * T + n] = __uint_as_float(Bhi.u[p] & 0xFFFF0000u);
  }
  #pragma unroll
  for (int d = 1; d < 64; d <<= 1) numer += __shfl_xor(numer, d);
  if (l == 0) { s_num[wv] = numer; s_K[wv] = Kacc; }
  __syncthreads();

  // ---- phase 2: wave 0 scans the 8 chunk matrices ----
  if (wv == 0) {
    const int t = n;
    float em0 = emb[head * T + t];
    float sc0 = (startT[t] + em0) * L2E;
    float m0 = sc0;
    #pragma unroll
    for (int d = 1; d < 32; d <<= 1) m0 = fmaxf(m0, __shfl_xor(m0, d));
    float e = exp2f(sc0 - m0);
    float Mtot = m0;

    for (int c = 0; c < 8; ++c) {
      const float* row = &s_mats[c][t * T];
      float acc = 0.0f;
      #pragma unroll
      for (int q = 0; q < 32; ++q) acc = fmaf(row[q], bcast_lane(e, q), acc);
      e = acc;
      Mtot += (float)s_K[c];
      float mx = e;
      #pragma unroll
      for (int d = 1; d < 32; d <<= 1) mx = fmaxf(mx, __shfl_xor(mx, d));
      int E = (int)((__float_as_uint(mx) >> 23) & 0xffu);
      e *= __uint_as_float((unsigned)(254 - E) << 23);
      Mtot += (float)(E - 127);
    }

    float fv = e * exp2f(endT[t] * L2E);
    #pragma unroll
    for (int d = 1; d < 32; d <<= 1) fv += __shfl_xor(fv, d);
    float denom = (Mtot + log2f(fv)) * LN2f;

    if (l == 0 && cnt > 0) {
      float ntot = 0.0f;
      for (int wq = 0; wq < 8; ++wq) ntot += s_num[wq];
      int th = s_tags[head], tt = s_tags[tail];
      ntot += startT[th] + bcast_lane(em0, th) + endT[tt];
      atomicAdd(&ws[0], (denom - ntot) / ((float)cnt + 1e-6f));
      atomicAdd(&ws[1], 1.0f);
    }
  }
}

extern "C" void kernel_launch(void* const* d_in, const int* in_sizes, int n_in,
                              void* d_out, int out_size, void* d_ws, size_t ws_size,
                              hipStream_t stream) {
  const float* em     = (const float*)d_in[0];
  const int*   tags   = (const int*)d_in[1];
  const int*   mask   = (const int*)d_in[2];
  const float* startT = (const float*)d_in[3];
  const float* trans  = (const float*)d_in[4];
  const float* endT   = (const float*)d_in[5];
  float* out = (float*)d_out;
  float* ws  = (float*)d_ws;

  const int B = in_sizes[0] / (S * T);

  crf_zero<<<1, 1, 0, stream>>>(ws);
  crf_main<<<B, 512, 0, stream>>>(em, tags, mask, startT, trans, endT, ws);
  crf_fin<<<1, 1, 0, stream>>>(ws, out);
}